// Round 9
// baseline (7738.268 us; speedup 1.0000x reference)
//
#include <hip/hip_runtime.h>

#define HSEQ 16777216   // 32*1024*512
#define NPL 32          // blocks per layer
#define NBLK 64

typedef __attribute__((ext_vector_type(8))) __bf16 bf16x8;
typedef __attribute__((ext_vector_type(4))) float f32x4;
typedef unsigned long long u64;
typedef unsigned int u32;

// x (B,T,64) f32 -> xbf [t][m][64] bf16
__global__ __launch_bounds__(256) void prep_x(const float* __restrict__ x,
                                              __bf16* __restrict__ xbf) {
    int idx = blockIdx.x * 256 + threadIdx.x;      // float4 units
    int k4 = idx & 15;
    int t  = (idx >> 4) & 1023;
    int m  = idx >> 14;
    float4 v = ((const float4*)x)[idx];
    __bf16* d = xbf + (size_t)t * 2048 + m * 64 + k4 * 4;
    d[0] = (__bf16)v.x; d[1] = (__bf16)v.y; d[2] = (__bf16)v.z; d[3] = (__bf16)v.w;
}

// Agent-scope relaxed accesses: coherent at the LLC, word-atomic (PROVEN R3/R4/R6).
__device__ __forceinline__ u64 llc_load64(const u64* p) {
    return __hip_atomic_load(p, __ATOMIC_RELAXED, __HIP_MEMORY_SCOPE_AGENT);
}
__device__ __forceinline__ u32 llc_load32(const u32* p) {
    return __hip_atomic_load(p, __ATOMIC_RELAXED, __HIP_MEMORY_SCOPE_AGENT);
}
__device__ __forceinline__ void llc_store64(u64* p, u64 v) {
    __hip_atomic_store(p, v, __ATOMIC_RELAXED, __HIP_MEMORY_SCOPE_AGENT);
}
__device__ __forceinline__ void llc_store32(u32* p, u32 v) {
    __hip_atomic_store(p, v, __ATOMIC_RELAXED, __HIP_MEMORY_SCOPE_AGENT);
}

__device__ __forceinline__ float fsig(float v)  { return 1.f / (1.f + __expf(-v)); }
__device__ __forceinline__ float ftanh(float v) { return 1.f - 2.f / (__expf(2.f * v) + 1.f); }

// Fragment byte offset (verified R6): kt = k-tile, mt = batch half, sub=(k>>3)&3,
// r=m&15, bis=byte within 16B slot. XOR swizzle keeps reads a pure permutation.
__device__ __forceinline__ int frag_byte(int kt, int mt, int sub, int r, int bis) {
    return (((kt << 1) + mt) << 10) + (sub << 8) + (((r ^ sub ^ ((kt & 1) << 2)) & 15) << 4) + bis;
}

#define GUARD (1 << 18)

// Tagged-word exchange (R4 protocol, proven): u64 word = [tag:32 | 2 x bf16].
// h0tag: depth-4 slots of 8192 words; h1tag: depth-2. Producer at step s writes
// slot s&D-1 with tag s+1, fire-and-forget. Consumer polls its own 16 words.
// Slot-reuse safety: self-layers by tag data-dependence induction; h0 vs L1
// readers by prog1 backpressure (L0 step s waits prog1 >= s-2). All polls bounded.
template<int LAYER>
__device__ void run_layer(
    int sub, int tid,
    const __bf16* __restrict__ xbf,
    const float* __restrict__ Wih, const float* __restrict__ Whh,
    const float* __restrict__ bih, const float* __restrict__ bhh,
    u64* h0tag, u64* h1tag, u32* prog1,
    float* __restrict__ hs_out, float* __restrict__ cs_out, char* smem)
{
    constexpr int KT = LAYER ? 32 : 18;   // k-tiles of 32 (K=1024 / K=576)
    const int hd0   = sub * 16;
    const int lane  = tid & 63;
    const int wid   = tid >> 6;
    const int mtile = wid & 1;
    const int ntile = wid >> 1;
    const int koff  = (lane >> 4) << 3;

    // ---- stage weight B-fragments into registers (once) ----
    bf16x8 wfr[KT];
    {
        const int n   = lane & 15;
        const int row = ntile * 512 + hd0 + n;   // PyTorch gate-stacked row
#pragma unroll
        for (int kt = 0; kt < KT; ++kt) {
            int k0 = kt * 32 + koff;
            const float* wp;
            if (LAYER == 0)
                wp = (k0 < 64) ? (Wih + (size_t)row * 64 + k0)
                               : (Whh + (size_t)row * 512 + (k0 - 64));
            else
                wp = (k0 < 512) ? (Wih + (size_t)row * 512 + k0)
                                : (Whh + (size_t)row * 512 + (k0 - 512));
            float4 f0 = ((const float4*)wp)[0];
            float4 f1 = ((const float4*)wp)[1];
            bf16x8 w;
            w[0]=(__bf16)f0.x; w[1]=(__bf16)f0.y; w[2]=(__bf16)f0.z; w[3]=(__bf16)f0.w;
            w[4]=(__bf16)f1.x; w[5]=(__bf16)f1.y; w[6]=(__bf16)f1.z; w[7]=(__bf16)f1.w;
            wfr[kt] = w;
        }
    }

    // ---- update-thread identity: tid<256, each owns 2 adjacent hidden dims ----
    const int um = tid >> 3, j2 = tid & 7;
    float bg[4][2];
    if (tid < 256) {
#pragma unroll
        for (int g = 0; g < 4; ++g)
#pragma unroll
            for (int p = 0; p < 2; ++p) {
                int r = g * 512 + hd0 + 2 * j2 + p;
                bg[g][p] = bih[r] + bhh[r];
            }
    }
    float c0 = 0.f, c1 = 0.f;
    float* gates = (float*)(smem + 65536);   // [32][65]

    if (LAYER == 1 && tid == 0) llc_store32(prog1 + sub * 32, 1u);  // "polls of step 0 done"

    const int rr = lane & 15, gg4 = lane >> 4;
    const int S0 = LAYER ? 1 : 0;
    const int S1 = LAYER ? 1025 : 1024;

    for (int s = S0; s < S1; ++s) {
        const int t = LAYER ? s - 1 : s;

        if (LAYER == 0) {
            // x(t) prefetch
            const int xm = tid >> 4, xc = tid & 15;
            u64 vx = *(const u64*)(xbf + (size_t)t * 2048 + xm * 64 + xc * 4);

            // tagged poll of h0(s-1): slot (s-1)&3, want tag s (s=0: memset 0)
            const u64* tb = h0tag + (size_t)((s + 3) & 3) * 8192 + tid;
            u64 va[16];
            u32 pend = 0xFFFFu;
            const u32 want = (u32)s;
#pragma unroll
            for (int i = 0; i < 16; ++i) {
                va[i] = llc_load64(tb + i * 512);
                if ((u32)(va[i] >> 32) == want) pend &= ~(1u << i);
            }
            // backpressure: L1 must have finished polling h0(s-4) before we overwrite slot s&3
            if (s >= 3 && tid < NPL) {
                const u32* pp = prog1 + tid * 32;
                int guard = GUARD;
                while ((int)llc_load32(pp) < s - 2 && --guard) __builtin_amdgcn_s_sleep(1);
            }
            int guard = GUARD;
            while (pend && --guard) {
#pragma unroll
                for (int i = 0; i < 16; ++i) {
                    if (pend & (1u << i)) {
                        u64 v0 = llc_load64(tb + i * 512);
                        if ((u32)(v0 >> 32) == want) { va[i] = v0; pend &= ~(1u << i); }
                    }
                }
                if (pend) __builtin_amdgcn_s_sleep(1);
            }
            // stage x frag (kt 0..1), u64 granule
            *(u64*)(smem + frag_byte(xc >> 3, xm >> 4, (xc >> 1) & 3, xm & 15, (xc & 1) << 3)) = vx;
            // stage h payloads (kt 2..17), u32 granules
#pragma unroll
            for (int i = 0; i < 16; ++i) {
                int w = tid + i * 512;
                int m = w >> 8, k0 = (w & 255) << 1;
                *(u32*)(smem + frag_byte(2 + (k0 >> 5), m >> 4, (k0 >> 3) & 3, m & 15, (k0 & 6) << 1)) = (u32)va[i];
            }
        } else {
            // tagged polls: h0(s-1) slot (s-1)&3 want s ; h1(s-2) slot (s-1)&1 want s (s==1: 0)
            const u64* ta = h0tag + (size_t)((s + 3) & 3) * 8192 + tid;
            const u64* tb = h1tag + (size_t)((s + 1) & 1) * 8192 + tid;
            const u32 wantA = (u32)s;
            const u32 wantB = (s == 1) ? 0u : (u32)s;
            u64 va[16], vb[16];
            u32 pa = 0xFFFFu, pb = 0xFFFFu;
#pragma unroll
            for (int i = 0; i < 16; ++i) {
                va[i] = llc_load64(ta + i * 512);
                if ((u32)(va[i] >> 32) == wantA) pa &= ~(1u << i);
            }
#pragma unroll
            for (int i = 0; i < 16; ++i) {
                vb[i] = llc_load64(tb + i * 512);
                if ((u32)(vb[i] >> 32) == wantB) pb &= ~(1u << i);
            }
            int guard = GUARD;
            while ((pa | pb) && --guard) {
#pragma unroll
                for (int i = 0; i < 16; ++i) {
                    if (pa & (1u << i)) {
                        u64 v0 = llc_load64(ta + i * 512);
                        if ((u32)(v0 >> 32) == wantA) { va[i] = v0; pa &= ~(1u << i); }
                    }
                }
#pragma unroll
                for (int i = 0; i < 16; ++i) {
                    if (pb & (1u << i)) {
                        u64 v0 = llc_load64(tb + i * 512);
                        if ((u32)(v0 >> 32) == wantB) { vb[i] = v0; pb &= ~(1u << i); }
                    }
                }
                if (pa | pb) __builtin_amdgcn_s_sleep(1);
            }
            // stage h0 payloads (kt 0..15) and h1 payloads (kt 16..31), u32 granules
#pragma unroll
            for (int i = 0; i < 16; ++i) {
                int w = tid + i * 512;
                int m = w >> 8, k0 = (w & 255) << 1;
                *(u32*)(smem + frag_byte(k0 >> 5, m >> 4, (k0 >> 3) & 3, m & 15, (k0 & 6) << 1)) = (u32)va[i];
            }
#pragma unroll
            for (int i = 0; i < 16; ++i) {
                int w = tid + i * 512;
                int m = w >> 8, k0 = (w & 255) << 1;
                *(u32*)(smem + frag_byte(16 + (k0 >> 5), m >> 4, (k0 >> 3) & 3, m & 15, (k0 & 6) << 1)) = (u32)vb[i];
            }
        }
        __syncthreads();   // sync_A: staging visible, all polls complete

        if (LAYER == 1 && tid == 0)
            llc_store32(prog1 + sub * 32, (u32)(s + 1));   // "polls of step s complete"

        // ---- MFMA: full-K gates tile (weights in registers) ----
        f32x4 acc0 = {0.f,0.f,0.f,0.f}, acc1 = {0.f,0.f,0.f,0.f};
#pragma unroll
        for (int kt = 0; kt < KT; ++kt) {
            bf16x8 a = *(const bf16x8*)(smem + frag_byte(kt, mtile, gg4, rr, 0));
            if (kt & 1) acc1 = __builtin_amdgcn_mfma_f32_16x16x32_bf16(a, wfr[kt], acc1, 0, 0, 0);
            else        acc0 = __builtin_amdgcn_mfma_f32_16x16x32_bf16(a, wfr[kt], acc0, 0, 0, 0);
        }
        f32x4 acc = acc0 + acc1;
#pragma unroll
        for (int r = 0; r < 4; ++r)
            gates[(mtile * 16 + gg4 * 4 + r) * 65 + ntile * 16 + rr] = acc[r];
        __syncthreads();   // sync_B: gates ready

        // ---- elementwise update + fire-and-forget tagged publish ----
        if (tid < 256) {
            const int q0 = 2 * j2;
            float gi0 = gates[um * 65 + q0]          + bg[0][0];
            float gi1 = gates[um * 65 + q0 + 1]      + bg[0][1];
            float gf0 = gates[um * 65 + 16 + q0]     + bg[1][0];
            float gf1 = gates[um * 65 + 16 + q0 + 1] + bg[1][1];
            float gg0 = gates[um * 65 + 32 + q0]     + bg[2][0];
            float gg1 = gates[um * 65 + 32 + q0 + 1] + bg[2][1];
            float go0 = gates[um * 65 + 48 + q0]     + bg[3][0];
            float go1 = gates[um * 65 + 48 + q0 + 1] + bg[3][1];
            c0 = fsig(gf0) * c0 + fsig(gi0) * ftanh(gg0);
            c1 = fsig(gf1) * c1 + fsig(gi1) * ftanh(gg1);
            float h0v = fsig(go0) * ftanh(c0);
            float h1v = fsig(go1) * ftanh(c1);

            __bf16 hb0 = (__bf16)h0v, hb1 = (__bf16)h1v;
            u32 pack = (u32)__builtin_bit_cast(unsigned short, hb0)
                     | ((u32)__builtin_bit_cast(unsigned short, hb1) << 16);
            const int widx = um * 256 + sub * 8 + j2;
            u64 word = ((u64)(u32)(s + 1) << 32) | (u64)pack;
            if (LAYER == 0) llc_store64(h0tag + (size_t)(s & 3) * 8192 + widx, word);
            else            llc_store64(h1tag + (size_t)(s & 1) * 8192 + widx, word);

            // bulk outputs after the publish (overlap next step's poll)
            size_t base = ((size_t)um * 1024 + t) * 512 + hd0 + q0;
            u64 hv = (u64)__builtin_bit_cast(u32, h0v) | ((u64)__builtin_bit_cast(u32, h1v) << 32);
            u64 cv = (u64)__builtin_bit_cast(u32, c0)  | ((u64)__builtin_bit_cast(u32, c1)  << 32);
            __builtin_nontemporal_store(hv, (u64*)(hs_out + base));
            __builtin_nontemporal_store(cv, (u64*)(cs_out + base));
        }
    }
}

__global__ __launch_bounds__(512, 1) void lstm2(
    const __bf16* __restrict__ xbf,
    const float* __restrict__ Wih0, const float* __restrict__ Whh0,
    const float* __restrict__ bih0, const float* __restrict__ bhh0,
    const float* __restrict__ Wih1, const float* __restrict__ Whh1,
    const float* __restrict__ bih1, const float* __restrict__ bhh1,
    u64* h0tag, u64* h1tag, u32* prog1, float* __restrict__ dout)
{
    __shared__ alignas(16) char smem[73984];   // 64KB frags + 8.3KB gates
    const int tid = threadIdx.x, blk = blockIdx.x;
    float* hsbase = dout + 32768;
    if (blk < NPL)
        run_layer<0>(blk, tid, xbf, Wih0, Whh0, bih0, bhh0, h0tag, h1tag, prog1,
                     hsbase, hsbase + 2 * (size_t)HSEQ, smem);
    else
        run_layer<1>(blk - NPL, tid, xbf, Wih1, Whh1, bih1, bhh1, h0tag, h1tag, prog1,
                     hsbase + (size_t)HSEQ, hsbase + 3 * (size_t)HSEQ, smem);
}

// out[tok] = W2 @ relu(W1 @ h1[tok] + b1) + b2 ; 16 tokens per block
__global__ __launch_bounds__(256) void head_kernel(
    const float* __restrict__ h1s, const float* __restrict__ W1,
    const float* __restrict__ b1,  const float* __restrict__ W2,
    const float* __restrict__ b2,  float* __restrict__ out)
{
    __shared__ alignas(16) float hl[16][512];
    __shared__ float red[16][257];
    const int tid = threadIdx.x;
    const size_t tok0 = (size_t)blockIdx.x * 16;

    const float4* src = (const float4*)(h1s + tok0 * 512);
    float4* dst = (float4*)(&hl[0][0]);
    for (int i = tid; i < 2048; i += 256) dst[i] = src[i];
    __syncthreads();

    float acc[16];
#pragma unroll
    for (int i = 0; i < 16; ++i) acc[i] = 0.f;
    const float4* wrow = (const float4*)(W1 + (size_t)tid * 512);
    for (int k4 = 0; k4 < 128; ++k4) {
        float4 w = wrow[k4];
#pragma unroll
        for (int i = 0; i < 16; ++i) {
            float4 h = ((const float4*)&hl[i][0])[k4];
            acc[i] += w.x * h.x + w.y * h.y + w.z * h.z + w.w * h.w;
        }
    }
    float w2 = W2[tid];
    float bb1 = b1[tid];
#pragma unroll
    for (int i = 0; i < 16; ++i) {
        float hid = acc[i] + bb1;
        red[i][tid] = w2 * (hid > 0.f ? hid : 0.f);
    }
    __syncthreads();
    if (tid < 16) {
        float ssum = b2[0];
        for (int j = 0; j < 256; ++j) ssum += red[tid][j];
        out[tok0 + tid] = ssum;
    }
}

extern "C" void kernel_launch(void* const* d_in, const int* in_sizes, int n_in,
                              void* d_out, int out_size, void* d_ws, size_t ws_size,
                              hipStream_t stream) {
    const float* x    = (const float*)d_in[0];
    const float* Wih0 = (const float*)d_in[1];
    const float* Whh0 = (const float*)d_in[2];
    const float* bih0 = (const float*)d_in[3];
    const float* bhh0 = (const float*)d_in[4];
    const float* Wih1 = (const float*)d_in[5];
    const float* Whh1 = (const float*)d_in[6];
    const float* bih1 = (const float*)d_in[7];
    const float* bhh1 = (const float*)d_in[8];
    const float* W1   = (const float*)d_in[9];
    const float* b1   = (const float*)d_in[10];
    const float* W2   = (const float*)d_in[11];
    const float* b2   = (const float*)d_in[12];
    float* out = (float*)d_out;

    char* ws = (char*)d_ws;
    u32* prog1 = (u32*)ws;                             // 32 words, 128B stride (4KB)
    u64* h0tag = (u64*)(ws + 4096);                    // 4 slots x 8192 x 8B = 256KB
    u64* h1tag = (u64*)(ws + 4096 + 262144);           // 2 slots x 8192 x 8B = 128KB
    __bf16* xbf = (__bf16*)(ws + 4096 + 262144 + 131072);   // 4 MB

    // zero tags + progress every launch (graph-replay safe)
    hipMemsetAsync(ws, 0, 4096 + 262144 + 131072, stream);

    prep_x<<<2048, 256, 0, stream>>>(x, xbf);

    const __bf16* xbf_c = xbf;
    void* args[] = {
        (void*)&xbf_c,
        (void*)&Wih0, (void*)&Whh0, (void*)&bih0, (void*)&bhh0,
        (void*)&Wih1, (void*)&Whh1, (void*)&bih1, (void*)&bhh1,
        (void*)&h0tag, (void*)&h1tag, (void*)&prog1, (void*)&out
    };
    hipLaunchCooperativeKernel((const void*)lstm2, dim3(NBLK), dim3(512),
                               args, 0, stream);

    head_kernel<<<2048, 256, 0, stream>>>(out + 32768 + (size_t)HSEQ, W1, b1, W2, b2, out);
}

// Round 10
// 3610.642 us; speedup vs baseline: 2.1432x; 2.1432x over previous
//
#include <hip/hip_runtime.h>

#define HSEQ 16777216   // 32*1024*512
#define NPL 32          // blocks per layer
#define NBLK 64

typedef __attribute__((ext_vector_type(8))) __bf16 bf16x8;
typedef __attribute__((ext_vector_type(4))) float f32x4;
typedef __attribute__((ext_vector_type(4))) unsigned int u32x4;
typedef unsigned long long u64;
typedef unsigned int u32;

// x (B,T,64) f32 -> xbf [t][m][64] bf16
__global__ __launch_bounds__(256) void prep_x(const float* __restrict__ x,
                                              __bf16* __restrict__ xbf) {
    int idx = blockIdx.x * 256 + threadIdx.x;      // float4 units
    int k4 = idx & 15;
    int t  = (idx >> 4) & 1023;
    int m  = idx >> 14;
    float4 v = ((const float4*)x)[idx];
    __bf16* d = xbf + (size_t)t * 2048 + m * 64 + k4 * 4;
    d[0] = (__bf16)v.x; d[1] = (__bf16)v.y; d[2] = (__bf16)v.z; d[3] = (__bf16)v.w;
}

// Agent-scope relaxed atomics: LLC-coherent, word-atomic (proven R3/R4/R6/R9).
__device__ __forceinline__ u64 llc_load64(const u64* p) {
    return __hip_atomic_load(p, __ATOMIC_RELAXED, __HIP_MEMORY_SCOPE_AGENT);
}
__device__ __forceinline__ u32 llc_load32(const u32* p) {
    return __hip_atomic_load(p, __ATOMIC_RELAXED, __HIP_MEMORY_SCOPE_AGENT);
}
__device__ __forceinline__ void llc_store64(u64* p, u64 v) {
    __hip_atomic_store(p, v, __ATOMIC_RELAXED, __HIP_MEMORY_SCOPE_AGENT);
}
__device__ __forceinline__ void llc_store32(u32* p, u32 v) {
    __hip_atomic_store(p, v, __ATOMIC_RELAXED, __HIP_MEMORY_SCOPE_AGENT);
}

// One-shot bulk: 8 x dwordx4 (16B) LLC-direct loads (sc0 sc1 = bypass L1+L2),
// pipelined with a single vmcnt wait. Each 16B = 2 tagged u64 words.
__device__ __forceinline__ void llc_bulk8(const u64* b, u32x4 o[8]) {
    asm volatile(
        "global_load_dwordx4 %0, %8, off sc0 sc1\n\t"
        "global_load_dwordx4 %1, %9, off sc0 sc1\n\t"
        "global_load_dwordx4 %2, %10, off sc0 sc1\n\t"
        "global_load_dwordx4 %3, %11, off sc0 sc1\n\t"
        "global_load_dwordx4 %4, %12, off sc0 sc1\n\t"
        "global_load_dwordx4 %5, %13, off sc0 sc1\n\t"
        "global_load_dwordx4 %6, %14, off sc0 sc1\n\t"
        "global_load_dwordx4 %7, %15, off sc0 sc1\n\t"
        "s_waitcnt vmcnt(0)"
        : "=&v"(o[0]), "=&v"(o[1]), "=&v"(o[2]), "=&v"(o[3]),
          "=&v"(o[4]), "=&v"(o[5]), "=&v"(o[6]), "=&v"(o[7])
        : "v"(b), "v"(b + 1024), "v"(b + 2048), "v"(b + 3072),
          "v"(b + 4096), "v"(b + 5120), "v"(b + 6144), "v"(b + 7168)
        : "memory");
    __builtin_amdgcn_sched_barrier(0);
}

__device__ __forceinline__ float fsig(float v)  { return 1.f / (1.f + __expf(-v)); }
__device__ __forceinline__ float ftanh(float v) { return 1.f - 2.f / (__expf(2.f * v) + 1.f); }

// Fragment byte offset (verified R6/R9): kt, mtile, sub=(k>>3)&3, r=m&15, bis.
__device__ __forceinline__ int frag_byte(int kt, int mt, int sub, int r, int bis) {
    return (((kt << 1) + mt) << 10) + (sub << 8) + (((r ^ sub ^ ((kt & 1) << 2)) & 15) << 4) + bis;
}

#define FGUARD (1 << 22)
#define RGUARD (1 << 18)

// verify tags of 8 x u32x4 against want; returns pay[16] + pend mask
__device__ __forceinline__ u32 verify16(const u32x4 o[8], u32 want, u32 pay[16]) {
    u32 pend = 0;
#pragma unroll
    for (int k = 0; k < 8; ++k) {
        pay[2 * k]     = o[k].x; if (o[k].y != want) pend |= 1u << (2 * k);
        pay[2 * k + 1] = o[k].z; if (o[k].w != want) pend |= 1u << (2 * k + 1);
    }
    return pend;
}
__device__ __forceinline__ void retry16(const u64* slot, int tid, u32 want,
                                        u32 pay[16], u32 pend) {
    int guard = RGUARD;
    while (pend && --guard) {
#pragma unroll
        for (int i = 0; i < 16; ++i) {
            if (pend & (1u << i)) {
                u64 v = llc_load64(slot + 2 * tid + (i >> 1) * 1024 + (i & 1));
                if ((u32)(v >> 32) == want) { pay[i] = (u32)v; pend &= ~(1u << i); }
            }
        }
        if (pend) __builtin_amdgcn_s_sleep(1);
    }
}
// stage 16 payload u32s (2 bf16 each) into fragment region at base k-tile
__device__ __forceinline__ void stage16(char* smem, int base_kt, int tid, const u32 pay[16]) {
#pragma unroll
    for (int i = 0; i < 16; ++i) {
        int w = 2 * tid + (i >> 1) * 1024 + (i & 1);
        int m = w >> 8, k0 = (w & 255) << 1;
        *(u32*)(smem + frag_byte(base_kt + (k0 >> 5), m >> 4, (k0 >> 3) & 3, m & 15, (k0 & 6) << 1)) = pay[i];
    }
}

// One layer, persistent. 32 blocks/layer, 512 threads, weights in registers.
// Exchange: tagged u64 words [tag:32|2xbf16] in LLC; flags gate the one-shot bulk
// (fire-and-forget; tags catch flag-overtakes-data). h0tag depth-4, h1tag depth-2.
template<int LAYER>
__device__ void run_layer(
    int sub, int tid,
    const __bf16* __restrict__ xbf,
    const float* __restrict__ Wih, const float* __restrict__ Whh,
    const float* __restrict__ bih, const float* __restrict__ bhh,
    u64* h0tag, u64* h1tag, u32* flags,
    float* __restrict__ hs_out, float* __restrict__ cs_out, char* smem)
{
    constexpr int KT = LAYER ? 32 : 18;   // k-tiles of 32 (K=1024 / K=576)
    const int hd0   = sub * 16;
    const int lane  = tid & 63;
    const int wid   = tid >> 6;
    const int mtile = wid & 1;
    const int ntile = wid >> 1;
    const int koff  = (lane >> 4) << 3;
    const int blkid = LAYER * NPL + sub;

    // ---- stage weight B-fragments into registers (once) ----
    bf16x8 wfr[KT];
    {
        const int n   = lane & 15;
        const int row = ntile * 512 + hd0 + n;   // PyTorch gate-stacked row
#pragma unroll
        for (int kt = 0; kt < KT; ++kt) {
            int k0 = kt * 32 + koff;
            const float* wp;
            if (LAYER == 0)
                wp = (k0 < 64) ? (Wih + (size_t)row * 64 + k0)
                               : (Whh + (size_t)row * 512 + (k0 - 64));
            else
                wp = (k0 < 512) ? (Wih + (size_t)row * 512 + k0)
                                : (Whh + (size_t)row * 512 + (k0 - 512));
            float4 f0 = ((const float4*)wp)[0];
            float4 f1 = ((const float4*)wp)[1];
            bf16x8 w;
            w[0]=(__bf16)f0.x; w[1]=(__bf16)f0.y; w[2]=(__bf16)f0.z; w[3]=(__bf16)f0.w;
            w[4]=(__bf16)f1.x; w[5]=(__bf16)f1.y; w[6]=(__bf16)f1.z; w[7]=(__bf16)f1.w;
            wfr[kt] = w;
        }
    }

    // ---- update-thread identity: tid<256, each owns 2 adjacent hidden dims ----
    const int um = tid >> 3, j2 = tid & 7;
    float bg[4][2];
    if (tid < 256) {
#pragma unroll
        for (int g = 0; g < 4; ++g)
#pragma unroll
            for (int p = 0; p < 2; ++p) {
                int r = g * 512 + hd0 + 2 * j2 + p;
                bg[g][p] = bih[r] + bhh[r];
            }
    }
    float c0 = 0.f, c1 = 0.f;
    float* gates = (float*)(smem + 65536);        // [32][65]
    u32*   cnt   = (u32*)(smem + 65536 + 8448);   // wave-arrival counter

    if (tid == 0) *cnt = 0;
    if (LAYER == 1 && tid == 0) llc_store32(flags + blkid * 32, 1u);  // "done step 0"

    const int rr = lane & 15, gg4 = lane >> 4;
    const int S0 = LAYER ? 1 : 0;
    const int S1 = LAYER ? 1025 : 1024;
    int it = 0;

    for (int s = S0; s < S1; ++s, ++it) {
        const int t = LAYER ? s - 1 : s;
        u32x4 o[8];
        u32 pay[16];

        if (LAYER == 1) {
            // h0(s-1) is ~1 step old (L1 lags L0) -> bulk+verify+stage BEFORE flag wait.
            const u64* slotA = h0tag + (size_t)((s + 3) & 3) * 8192;
            llc_bulk8(slotA + 2 * tid, o);
            u32 pend = verify16(o, (u32)s, pay);
            if (pend) retry16(slotA, tid, (u32)s, pay, pend);
            stage16(smem, 0, tid, pay);   // kt 0..15 (safe: peers past prior sync_B)
        } else {
            // x(t) prefetch + stage (independent of barrier)
            const int xm = tid >> 4, xc = tid & 15;
            u64 vx = *(const u64*)(xbf + (size_t)t * 2048 + xm * 64 + xc * 4);
            *(u64*)(smem + frag_byte(xc >> 3, xm >> 4, (xc >> 1) & 3, xm & 15, (xc & 1) << 3)) = vx;
        }

        // ---- cheap flag gate: 1 flag per poller thread, with sleep ----
        if (LAYER == 0) {
            if (tid < 64) {
                int thr = (tid >= 32) ? (s - 2) : s;   // L1 backpressure vs L0 data-hint
                if (thr > 0) {
                    const u32* fp = flags + tid * 32;
                    int bound = FGUARD;
                    while ((int)llc_load32(fp) < thr && --bound) __builtin_amdgcn_s_sleep(1);
                }
            }
        } else {
            if (tid < 32) {   // L1 peers only (h1 self-recurrence); h0 covered by tags
                const u32* fp = flags + (NPL + tid) * 32;
                int bound = FGUARD;
                while ((int)llc_load32(fp) < s && --bound) __builtin_amdgcn_s_sleep(1);
            }
        }
        __syncthreads();

        // ---- one-shot bulk of the self-recurrence data ----
        if (LAYER == 0) {
            const u64* slot = h0tag + (size_t)((s + 3) & 3) * 8192;   // h0(s-1), want tag s
            llc_bulk8(slot + 2 * tid, o);
            u32 pend = verify16(o, (u32)s, pay);
            if (pend) retry16(slot, tid, (u32)s, pay, pend);
            stage16(smem, 2, tid, pay);   // kt 2..17
        } else {
            const u64* slot = h1tag + (size_t)((s + 1) & 1) * 8192;   // h1(s-2)
            const u32 want = (s == 1) ? 0u : (u32)s;
            llc_bulk8(slot + 2 * tid, o);
            u32 pend = verify16(o, want, pay);
            if (pend) retry16(slot, tid, want, pay, pend);
            stage16(smem, 16, tid, pay);  // kt 16..31
        }
        __syncthreads();   // staging visible

        // ---- MFMA: full-K gates tile (weights in registers) ----
        f32x4 acc0 = {0.f,0.f,0.f,0.f}, acc1 = {0.f,0.f,0.f,0.f};
#pragma unroll
        for (int kt = 0; kt < KT; ++kt) {
            bf16x8 a = *(const bf16x8*)(smem + frag_byte(kt, mtile, gg4, rr, 0));
            if (kt & 1) acc1 = __builtin_amdgcn_mfma_f32_16x16x32_bf16(a, wfr[kt], acc1, 0, 0, 0);
            else        acc0 = __builtin_amdgcn_mfma_f32_16x16x32_bf16(a, wfr[kt], acc0, 0, 0, 0);
        }
        f32x4 acc = acc0 + acc1;
#pragma unroll
        for (int r = 0; r < 4; ++r)
            gates[(mtile * 16 + gg4 * 4 + r) * 65 + ntile * 16 + rr] = acc[r];
        __syncthreads();   // gates ready

        // ---- elementwise update + fire-and-forget publish + flag ----
        if (tid < 256) {
            const int q0 = 2 * j2;
            float gi0 = gates[um * 65 + q0]          + bg[0][0];
            float gi1 = gates[um * 65 + q0 + 1]      + bg[0][1];
            float gf0 = gates[um * 65 + 16 + q0]     + bg[1][0];
            float gf1 = gates[um * 65 + 16 + q0 + 1] + bg[1][1];
            float gg0 = gates[um * 65 + 32 + q0]     + bg[2][0];
            float gg1 = gates[um * 65 + 32 + q0 + 1] + bg[2][1];
            float go0 = gates[um * 65 + 48 + q0]     + bg[3][0];
            float go1 = gates[um * 65 + 48 + q0 + 1] + bg[3][1];
            c0 = fsig(gf0) * c0 + fsig(gi0) * ftanh(gg0);
            c1 = fsig(gf1) * c1 + fsig(gi1) * ftanh(gg1);
            float h0v = fsig(go0) * ftanh(c0);
            float h1v = fsig(go1) * ftanh(c1);

            __bf16 hb0 = (__bf16)h0v, hb1 = (__bf16)h1v;
            u32 pack = (u32)__builtin_bit_cast(unsigned short, hb0)
                     | ((u32)__builtin_bit_cast(unsigned short, hb1) << 16);
            const int widx = um * 256 + sub * 8 + j2;
            u64 word = ((u64)(u32)(s + 1) << 32) | (u64)pack;
            if (LAYER == 0) llc_store64(h0tag + (size_t)(s & 3) * 8192 + widx, word);
            else            llc_store64(h1tag + (size_t)(s & 1) * 8192 + widx, word);

            // NO ack: last-arriving wave posts the flag fire-and-forget (tags cover race)
            if (lane == 0) {
                u32 old = atomicAdd(cnt, 1u);
                if (old == (u32)(it * 4 + 3))
                    llc_store32(flags + blkid * 32, (u32)(s + 1));
            }

            // bulk outputs after the publish (overlap next step's wait)
            size_t base = ((size_t)um * 1024 + t) * 512 + hd0 + q0;
            u64 hv = (u64)__builtin_bit_cast(u32, h0v) | ((u64)__builtin_bit_cast(u32, h1v) << 32);
            u64 cv = (u64)__builtin_bit_cast(u32, c0)  | ((u64)__builtin_bit_cast(u32, c1)  << 32);
            __builtin_nontemporal_store(hv, (u64*)(hs_out + base));
            __builtin_nontemporal_store(cv, (u64*)(cs_out + base));
        }
    }
}

__global__ __launch_bounds__(512, 1) void lstm2(
    const __bf16* __restrict__ xbf,
    const float* __restrict__ Wih0, const float* __restrict__ Whh0,
    const float* __restrict__ bih0, const float* __restrict__ bhh0,
    const float* __restrict__ Wih1, const float* __restrict__ Whh1,
    const float* __restrict__ bih1, const float* __restrict__ bhh1,
    u64* h0tag, u64* h1tag, u32* flags, float* __restrict__ dout)
{
    __shared__ alignas(16) char smem[74048];   // 64KB frags + 8.3KB gates + cnt
    const int tid = threadIdx.x, blk = blockIdx.x;
    float* hsbase = dout + 32768;
    if (blk < NPL)
        run_layer<0>(blk, tid, xbf, Wih0, Whh0, bih0, bhh0, h0tag, h1tag, flags,
                     hsbase, hsbase + 2 * (size_t)HSEQ, smem);
    else
        run_layer<1>(blk - NPL, tid, xbf, Wih1, Whh1, bih1, bhh1, h0tag, h1tag, flags,
                     hsbase + (size_t)HSEQ, hsbase + 3 * (size_t)HSEQ, smem);
}

// out[tok] = W2 @ relu(W1 @ h1[tok] + b1) + b2 ; 16 tokens per block
__global__ __launch_bounds__(256) void head_kernel(
    const float* __restrict__ h1s, const float* __restrict__ W1,
    const float* __restrict__ b1,  const float* __restrict__ W2,
    const float* __restrict__ b2,  float* __restrict__ out)
{
    __shared__ alignas(16) float hl[16][512];
    __shared__ float red[16][257];
    const int tid = threadIdx.x;
    const size_t tok0 = (size_t)blockIdx.x * 16;

    const float4* src = (const float4*)(h1s + tok0 * 512);
    float4* dst = (float4*)(&hl[0][0]);
    for (int i = tid; i < 2048; i += 256) dst[i] = src[i];
    __syncthreads();

    float acc[16];
#pragma unroll
    for (int i = 0; i < 16; ++i) acc[i] = 0.f;
    const float4* wrow = (const float4*)(W1 + (size_t)tid * 512);
    for (int k4 = 0; k4 < 128; ++k4) {
        float4 w = wrow[k4];
#pragma unroll
        for (int i = 0; i < 16; ++i) {
            float4 h = ((const float4*)&hl[i][0])[k4];
            acc[i] += w.x * h.x + w.y * h.y + w.z * h.z + w.w * h.w;
        }
    }
    float w2 = W2[tid];
    float bb1 = b1[tid];
#pragma unroll
    for (int i = 0; i < 16; ++i) {
        float hid = acc[i] + bb1;
        red[i][tid] = w2 * (hid > 0.f ? hid : 0.f);
    }
    __syncthreads();
    if (tid < 16) {
        float ssum = b2[0];
        for (int j = 0; j < 256; ++j) ssum += red[tid][j];
        out[tok0 + tid] = ssum;
    }
}

extern "C" void kernel_launch(void* const* d_in, const int* in_sizes, int n_in,
                              void* d_out, int out_size, void* d_ws, size_t ws_size,
                              hipStream_t stream) {
    const float* x    = (const float*)d_in[0];
    const float* Wih0 = (const float*)d_in[1];
    const float* Whh0 = (const float*)d_in[2];
    const float* bih0 = (const float*)d_in[3];
    const float* bhh0 = (const float*)d_in[4];
    const float* Wih1 = (const float*)d_in[5];
    const float* Whh1 = (const float*)d_in[6];
    const float* bih1 = (const float*)d_in[7];
    const float* bhh1 = (const float*)d_in[8];
    const float* W1   = (const float*)d_in[9];
    const float* b1   = (const float*)d_in[10];
    const float* W2   = (const float*)d_in[11];
    const float* b2   = (const float*)d_in[12];
    float* out = (float*)d_out;

    char* ws = (char*)d_ws;
    u32* flags = (u32*)ws;                             // 64 flags, 128B stride (8KB)
    u64* h0tag = (u64*)(ws + 8192);                    // 4 slots x 8192 x 8B = 256KB
    u64* h1tag = (u64*)(ws + 8192 + 262144);           // 2 slots x 8192 x 8B = 128KB
    __bf16* xbf = (__bf16*)(ws + 8192 + 262144 + 131072);   // 4 MB

    // zero flags + tags every launch (tag 0 == step-0 zeros; graph-replay safe)
    hipMemsetAsync(ws, 0, 8192 + 262144 + 131072, stream);

    prep_x<<<2048, 256, 0, stream>>>(x, xbf);

    const __bf16* xbf_c = xbf;
    void* args[] = {
        (void*)&xbf_c,
        (void*)&Wih0, (void*)&Whh0, (void*)&bih0, (void*)&bhh0,
        (void*)&Wih1, (void*)&Whh1, (void*)&bih1, (void*)&bhh1,
        (void*)&h0tag, (void*)&h1tag, (void*)&flags, (void*)&out
    };
    hipLaunchCooperativeKernel((const void*)lstm2, dim3(NBLK), dim3(512),
                               args, 0, stream);

    head_kernel<<<2048, 256, 0, stream>>>(out + 32768 + (size_t)HSEQ, W1, b1, W2, b2, out);
}